// Round 15
// baseline (204.936 us; speedup 1.0000x reference)
//
#include <hip/hip_runtime.h>
#include <hip/hip_bf16.h>

#define TN 24
#define LOG2E 1.4426950408889634f

// Output-dim permutation: D-position (a-tile, rho=4cp+q) holds logical dim
//   sigma(a,rho) = 32*(a>>1) + 8*(rho>>2) + 4*(a&1) + (rho&3)
// With all gate tables permuted by sigma, lane (er,cp)'s cvtpk'd h pairs are
// exactly the next step's B-frag dwords (k = logical dim) -> h stays in regs.

// ws layout (bytes):
//   0     : gic2 [24][256] f32 : per t {R|Z|Ni|bhn} x 64 permuted slots,
//           pre-scaled by log2e (R,Z) / 2log2e (Ni,bhn)       (24576)
//   24576 : wlc [96 f32]  (unscaled)                          (384)
//   24960 : wi frags bf16 [12][64]x16B (rows sigma-permuted)  (12288)
//   37248 : whh frags bf16 [24][64]x16B (rows sigma-permuted) (24576)
#define WS_GIC_F   0
#define WS_WLC_F   6144
#define WS_WI_B    24960
#define WS_WHH_B   37248

// dynamic LDS layout (bytes), total 61952 (2 blocks/CU):
#define L_GIC_OFF  0        // f32 [24][256]        24576
#define L_WI_OFF   24576    // 12 frags x 64 x 16B  12288
#define L_WHH_OFF  36864    // 24 frags x 64 x 16B  24576
#define L_WLC_OFF  61440    // 96 f32                 384
#define LDS_BYTES  61952

typedef __attribute__((ext_vector_type(8))) short bf16x8;
typedef __attribute__((ext_vector_type(4))) float f32x4;
typedef __attribute__((ext_vector_type(2))) float f32x2;

__device__ __forceinline__ ushort bf16rn(float f) {
    uint x = __float_as_uint(f);
    return (ushort)((x + 0x7fffu + ((x >> 16) & 1u)) >> 16);
}
__device__ __forceinline__ uint cvtpk_bf16(float lo, float hi) {
    uint r;
    asm("v_cvt_pk_bf16_f32 %0, %1, %2" : "=v"(r) : "v"(lo), "v"(hi));
    return r;
}
__device__ __forceinline__ float exp2p_(float x) {   // 2^x
    float r; asm("v_exp_f32 %0, %1" : "=v"(r) : "v"(x)); return r;
}
__device__ __forceinline__ float exp2n_(float x) {   // 2^-x (free neg modifier)
    float r; asm("v_exp_f32 %0, -%1" : "=v"(r) : "v"(x)); return r;
}
__device__ __forceinline__ float sigm(float v) {
    return __builtin_amdgcn_rcpf(1.0f + __expf(-v));
}
__device__ __forceinline__ int sigma_(int a, int rho) {
    return 32 * (a >> 1) + 8 * (rho >> 2) + 4 * (a & 1) + (rho & 3);
}

// ---------------- pre-kernel: permuted scaled tables in ws ----------------
extern "C" __global__ void __launch_bounds__(256)
traj_gru_pre(const float* __restrict__ Wloc, const float* __restrict__ bloc,
             const float* __restrict__ tt, const float* __restrict__ Wih,
             const float* __restrict__ Whh, const float* __restrict__ bih,
             const float* __restrict__ bhh, float* __restrict__ ws)
{
    const int b = blockIdx.x, tid = threadIdx.x;
    if (b < 12) {
        // wi bf16 frags: b 0-3 = R a-tiles, 4-7 = Z, 8-11 = N; rows sigma-permuted
        if (tid < 64) {
            const int er = tid & 15, cp = tid >> 4;
            int g = b >> 2, a = b & 3;
            float s = (g == 2) ? 2.0f * LOG2E : LOG2E;
            const float* src = Wih + (size_t)(g * 64 + sigma_(a, er)) * 64 + 8 * cp;
            union { ushort u[8]; bf16x8 v; } fr;
            #pragma unroll
            for (int j = 0; j < 8; ++j) fr.u[j] = bf16rn(s * src[j]);
            *(bf16x8*)((char*)ws + WS_WI_B + ((size_t)b * 64 + tid) * 16) = fr.v;
        }
    } else if (b < 36) {
        // whh frags: rows sigma-permuted, k-columns unpermuted
        if (tid < 64) {
            const int er = tid & 15, cp = tid >> 4;
            int t = b - 12, g = t >> 3, r = t & 7, a = r >> 1, f = r & 1;
            float s = (g == 2) ? 2.0f * LOG2E : LOG2E;
            const float* src = Whh + (size_t)(g * 64 + sigma_(a, er)) * 64 + 32 * f + 8 * cp;
            union { ushort u[8]; bf16x8 v; } fr;
            #pragma unroll
            for (int j = 0; j < 8; ++j) fr.u[j] = bf16rn(s * src[j]);
            *(bf16x8*)((char*)ws + WS_WHH_B + ((size_t)t * 64 + tid) * 16) = fr.v;
        }
    } else if (b < 38) {
        // gic2[t][s]: slot s -> block (R/Z/Ni/bhn), permuted dim d
        const int base = (b - 36) * 3072;
        for (int i = tid; i < 3072; i += 256) {
            int idx = base + i, t = idx >> 8, s = idx & 255;
            int blk = s >> 6, s64 = s & 63;
            int d = sigma_(s64 >> 4, s64 & 15);
            float val;
            if (blk < 3) {
                int g = blk * 64 + d;
                float acc = bih[g] + (g < 128 ? bhh[g] : 0.0f);
                const float* ttr = tt + t * 32;
                const float* wr  = Wih + g * 64 + 32;
                #pragma unroll
                for (int k = 0; k < 32; ++k) {
                    float e = ttr[k];
                    e = fmaxf(e, 0.2f * e);
                    acc = fmaf(wr[k], e, acc);
                }
                val = acc * (g < 128 ? LOG2E : 2.0f * LOG2E);
            } else {
                val = 2.0f * LOG2E * bhh[128 + d];
            }
            ws[WS_GIC_F + idx] = val;
        }
    } else {
        if (tid < 96) ws[WS_WLC_F + tid] = (tid < 64) ? Wloc[tid] : bloc[tid - 64];
    }
}

// ------- main kernel: h register-resident; gic2 in LDS; unroll-2 pipelining -------
extern "C" __global__ void __launch_bounds__(512, 4)
traj_gru_mfma(const float* __restrict__ x, const float* __restrict__ ws,
              const float* __restrict__ Wpred, const float* __restrict__ bpred,
              float* __restrict__ out)
{
    extern __shared__ __align__(16) char L[];
    float* gicS = (float*)(L + L_GIC_OFF);
    char*  wiS  = L + L_WI_OFF;
    char*  whhS = L + L_WHH_OFF;
    float* wlcS = (float*)(L + L_WLC_OFF);

    const int tid  = threadIdx.x;
    const int lane = tid & 63;
    const int wid  = tid >> 6;       // wave 0..7
    const int er   = lane & 15;
    const int cp   = lane >> 4;

    // ---- stage tables ws -> LDS (coalesced) ----
    {
        const float4* g4 = (const float4*)(ws + WS_GIC_F);
        float4* s4 = (float4*)gicS;
        for (int i = tid; i < (TN * 256) / 4; i += 512) s4[i] = g4[i];
    }
    for (int i = tid; i < 36 * 64; i += 512) {
        int f = i >> 6, l = i & 63;
        if (f < 12)
            *(bf16x8*)(wiS + ((size_t)f * 64 + l) * 16) =
                *(const bf16x8*)((const char*)ws + WS_WI_B + (size_t)i * 16);
        else
            *(bf16x8*)(whhS + ((size_t)(f - 12) * 64 + l) * 16) =
                *(const bf16x8*)((const char*)ws + WS_WHH_B + ((size_t)(f - 12) * 64 + l) * 16);
    }
    if (tid < 96) wlcS[tid] = ws[WS_WLC_F + tid];
    __syncthreads();   // the only barrier

    const f32x2* wlc2 = (const f32x2*)wlcS;

    // ---- main loop: wave owns 16 elements; h state in registers ----
    const long long eg = (long long)(blockIdx.x * 8 + wid) * 16 + er;
    const float* xr = x + eg * (TN * 2);

    f32x2 hold2[4][2];           // f32 master state (permuted dims)
    uint  hf[8];                 // bf16 h pairs == next step's B-frag dwords
    #pragma unroll
    for (int a = 0; a < 4; ++a) {
        hf[2 * a] = 0u; hf[2 * a + 1] = 0u;
        #pragma unroll
        for (int p = 0; p < 2; ++p) hold2[a][p] = (f32x2){0.0f, 0.0f};
    }

    const f32x2 one2    = {1.0f, 1.0f};
    const f32x2 negtwo2 = {-2.0f, -2.0f};

    float2 xv = *(const float2*)(xr);   // t=0 prefetched

    #pragma unroll 2
    for (int t = 0; t < TN; ++t) {
        // accumulator init from gic2 (LDS, issued first so exf work hides latency)
        const float* gt = gicS + t * 256;
        f32x4 accR[4], accZ[4], accNi[4], accNh[4];
        #pragma unroll
        for (int a = 0; a < 4; ++a) {
            accR[a]  = *(const f32x4*)(gt + a * 16 + 4 * cp);
            accZ[a]  = *(const f32x4*)(gt + 64 + a * 16 + 4 * cp);
            accNi[a] = *(const f32x4*)(gt + 128 + a * 16 + 4 * cp);
            accNh[a] = *(const f32x4*)(gt + 192 + a * 16 + 4 * cp);
        }

        const int tn = (t + 1 < TN) ? t + 1 : TN - 1;
        float2 xv_next = *(const float2*)(xr + tn * 2);

        // ex B-frag: ex[k = 8cp+j][elem = er]
        union { uint u[4]; bf16x8 v; } exf;
        {
            f32x2 xx = {xv.x, xv.x}, yy = {xv.y, xv.y};
            #pragma unroll
            for (int jp = 0; jp < 4; ++jp) {
                int kp = 4 * cp + jp;
                f32x2 w1 = wlc2[kp], w2 = wlc2[16 + kp], bl = wlc2[32 + kp];
                f32x2 v = __builtin_elementwise_fma(xx, w1,
                          __builtin_elementwise_fma(yy, w2, bl));
                exf.u[jp] = cvtpk_bf16(fmaxf(v.x, 0.2f * v.x), fmaxf(v.y, 0.2f * v.y));
            }
        }

        // input-part MFMAs (K=32), weights from LDS
        #pragma unroll
        for (int a = 0; a < 4; ++a) {
            bf16x8 wr = *(const bf16x8*)(wiS + ((size_t)a * 64 + lane) * 16);
            bf16x8 wz = *(const bf16x8*)(wiS + ((size_t)(4 + a) * 64 + lane) * 16);
            bf16x8 wn = *(const bf16x8*)(wiS + ((size_t)(8 + a) * 64 + lane) * 16);
            accR[a]  = __builtin_amdgcn_mfma_f32_16x16x32_bf16(wr, exf.v, accR[a], 0, 0, 0);
            accZ[a]  = __builtin_amdgcn_mfma_f32_16x16x32_bf16(wz, exf.v, accZ[a], 0, 0, 0);
            accNi[a] = __builtin_amdgcn_mfma_f32_16x16x32_bf16(wn, exf.v, accNi[a], 0, 0, 0);
        }

        // recurrent MFMAs: B-frags assembled directly from hf registers
        if (t > 0) {
            union { uint u[4]; bf16x8 v; } h0, h1;
            h0.u[0] = hf[0]; h0.u[1] = hf[1]; h0.u[2] = hf[2]; h0.u[3] = hf[3];
            h1.u[0] = hf[4]; h1.u[1] = hf[5]; h1.u[2] = hf[6]; h1.u[3] = hf[7];
            #pragma unroll
            for (int a = 0; a < 4; ++a) {
                bf16x8 wr0 = *(const bf16x8*)(whhS + ((size_t)(a * 2 + 0) * 64 + lane) * 16);
                bf16x8 wr1 = *(const bf16x8*)(whhS + ((size_t)(a * 2 + 1) * 64 + lane) * 16);
                accR[a] = __builtin_amdgcn_mfma_f32_16x16x32_bf16(wr0, h0.v, accR[a], 0, 0, 0);
                accR[a] = __builtin_amdgcn_mfma_f32_16x16x32_bf16(wr1, h1.v, accR[a], 0, 0, 0);
                bf16x8 wz0 = *(const bf16x8*)(whhS + ((size_t)(8 + a * 2 + 0) * 64 + lane) * 16);
                bf16x8 wz1 = *(const bf16x8*)(whhS + ((size_t)(8 + a * 2 + 1) * 64 + lane) * 16);
                accZ[a] = __builtin_amdgcn_mfma_f32_16x16x32_bf16(wz0, h0.v, accZ[a], 0, 0, 0);
                accZ[a] = __builtin_amdgcn_mfma_f32_16x16x32_bf16(wz1, h1.v, accZ[a], 0, 0, 0);
                bf16x8 wn0 = *(const bf16x8*)(whhS + ((size_t)(16 + a * 2 + 0) * 64 + lane) * 16);
                bf16x8 wn1 = *(const bf16x8*)(whhS + ((size_t)(16 + a * 2 + 1) * 64 + lane) * 16);
                accNh[a] = __builtin_amdgcn_mfma_f32_16x16x32_bf16(wn0, h0.v, accNh[a], 0, 0, 0);
                accNh[a] = __builtin_amdgcn_mfma_f32_16x16x32_bf16(wn1, h1.v, accNh[a], 0, 0, 0);
            }
        }

        // epilogue: packed-f32 gate math; h pairs -> hf registers (no LDS)
        #pragma unroll
        for (int a = 0; a < 4; ++a) {
            #pragma unroll
            for (int p = 0; p < 2; ++p) {
                f32x2 aR  = {accR[a][2 * p],  accR[a][2 * p + 1]};
                f32x2 aZ  = {accZ[a][2 * p],  accZ[a][2 * p + 1]};
                f32x2 aNi = {accNi[a][2 * p], accNi[a][2 * p + 1]};
                f32x2 aNh = {accNh[a][2 * p], accNh[a][2 * p + 1]};
                f32x2 eR = {exp2n_(aR.x), exp2n_(aR.y)};
                f32x2 eZ = {exp2n_(aZ.x), exp2n_(aZ.y)};
                f32x2 dR = eR + one2;
                f32x2 dZ = eZ + one2;
                f32x2 r  = {__builtin_amdgcn_rcpf(dR.x), __builtin_amdgcn_rcpf(dR.y)};
                f32x2 z  = {__builtin_amdgcn_rcpf(dZ.x), __builtin_amdgcn_rcpf(dZ.y)};
                f32x2 np = __builtin_elementwise_fma(r, aNh, aNi);     // 2log2e * npre
                f32x2 e2 = {exp2p_(np.x), exp2p_(np.y)};
                f32x2 d2 = e2 + one2;
                f32x2 rc = {__builtin_amdgcn_rcpf(d2.x), __builtin_amdgcn_rcpf(d2.y)};
                f32x2 n  = __builtin_elementwise_fma(rc, negtwo2, one2);  // tanh
                f32x2 hm = hold2[a][p] - n;
                f32x2 h  = __builtin_elementwise_fma(z, hm, n);
                hold2[a][p] = h;
                hf[2 * a + p] = cvtpk_bf16(h.x, h.y);
            }
        }

        xv = xv_next;
    }

    // ---- prediction head (Wpred read at permuted dims) ----
    float part = 0.0f;
    #pragma unroll
    for (int a = 0; a < 4; ++a) {
        #pragma unroll
        for (int p = 0; p < 2; ++p) {
            int base = 32 * (a >> 1) + 8 * cp + 4 * (a & 1) + 2 * p;
            f32x2 wp = *(const f32x2*)(Wpred + base);
            part = fmaf(hold2[a][p].x, wp.x, part);
            part = fmaf(hold2[a][p].y, wp.y, part);
        }
    }
    part += __shfl_xor(part, 16);
    part += __shfl_xor(part, 32);
    if (cp == 0) out[eg] = sigm(part + bpred[0]);
}

extern "C" void kernel_launch(void* const* d_in, const int* in_sizes, int n_in,
                              void* d_out, int out_size, void* d_ws, size_t ws_size,
                              hipStream_t stream) {
    const float* x     = (const float*)d_in[0];
    const float* Wloc  = (const float*)d_in[1];
    const float* bloc  = (const float*)d_in[2];
    const float* tt    = (const float*)d_in[3];
    const float* Wih   = (const float*)d_in[4];
    const float* Whh   = (const float*)d_in[5];
    const float* bih   = (const float*)d_in[6];
    const float* bhh   = (const float*)d_in[7];
    const float* Wpred = (const float*)d_in[8];
    const float* bpred = (const float*)d_in[9];
    float* out = (float*)d_out;
    float* ws  = (float*)d_ws;

    (void)hipFuncSetAttribute((const void*)traj_gru_mfma,
                              hipFuncAttributeMaxDynamicSharedMemorySize, LDS_BYTES);

    hipLaunchKernelGGL(traj_gru_pre, dim3(39), dim3(256), 0, stream,
                       Wloc, bloc, tt, Wih, Whh, bih, bhh, ws);
    // 65536 elements / (8 waves * 16 elem) = 512 blocks of 512 threads = 2 blocks/CU
    hipLaunchKernelGGL(traj_gru_mfma, dim3(512), dim3(512), LDS_BYTES, stream,
                       x, ws, Wpred, bpred, out);
}

// Round 16
// 106.949 us; speedup vs baseline: 1.9162x; 1.9162x over previous
//
#include <hip/hip_runtime.h>
#include <hip/hip_bf16.h>

#define TN 24
#define LOG2E 1.4426950408889634f

// Output-dim permutation: D-position (a-tile, rho=4cp+q) holds logical dim
//   sigma(a,rho) = 32*(a>>1) + 8*(rho>>2) + 4*(a&1) + (rho&3)
// With all gate tables permuted by sigma, lane (er,cp)'s cvtpk'd h pairs are
// exactly the next step's B-frag dwords (k = logical dim) -> h stays in regs.

// ws layout (bytes):
//   0     : gic2 [24][256] f32 : per t {R|Z|Ni|bhn} x 64 permuted slots,
//           pre-scaled by log2e (R,Z) / 2log2e (Ni,bhn)       (24576)
//   24576 : wlc [96 f32]  (unscaled)                          (384)
//   24960 : wi frags bf16 [12][64]x16B (rows sigma-permuted)  (12288)
//   37248 : whh frags bf16 [24][64]x16B (rows sigma-permuted) (24576)
#define WS_GIC_F   0
#define WS_WLC_F   6144
#define WS_WI_B    24960
#define WS_WHH_B   37248

// dynamic LDS layout (bytes), total 61952 (2 blocks/CU):
#define L_GIC_OFF  0        // f32 [24][256]        24576
#define L_WI_OFF   24576    // 12 frags x 64 x 16B  12288
#define L_WHH_OFF  36864    // 24 frags x 64 x 16B  24576
#define L_WLC_OFF  61440    // 96 f32                 384
#define LDS_BYTES  61952

typedef __attribute__((ext_vector_type(8))) short bf16x8;
typedef __attribute__((ext_vector_type(4))) float f32x4;
typedef __attribute__((ext_vector_type(2))) float f32x2;

__device__ __forceinline__ ushort bf16rn(float f) {
    uint x = __float_as_uint(f);
    return (ushort)((x + 0x7fffu + ((x >> 16) & 1u)) >> 16);
}
__device__ __forceinline__ uint cvtpk_bf16(float lo, float hi) {
    uint r;
    asm("v_cvt_pk_bf16_f32 %0, %1, %2" : "=v"(r) : "v"(lo), "v"(hi));
    return r;
}
__device__ __forceinline__ float exp2p_(float x) {   // 2^x
    float r; asm("v_exp_f32 %0, %1" : "=v"(r) : "v"(x)); return r;
}
__device__ __forceinline__ float exp2n_(float x) {   // 2^-x (free neg modifier)
    float r; asm("v_exp_f32 %0, -%1" : "=v"(r) : "v"(x)); return r;
}
__device__ __forceinline__ float sigm(float v) {
    return __builtin_amdgcn_rcpf(1.0f + __expf(-v));
}
__device__ __forceinline__ int sigma_(int a, int rho) {
    return 32 * (a >> 1) + 8 * (rho >> 2) + 4 * (a & 1) + (rho & 3);
}

// ---------------- pre-kernel: permuted scaled tables in ws ----------------
extern "C" __global__ void __launch_bounds__(256)
traj_gru_pre(const float* __restrict__ Wloc, const float* __restrict__ bloc,
             const float* __restrict__ tt, const float* __restrict__ Wih,
             const float* __restrict__ Whh, const float* __restrict__ bih,
             const float* __restrict__ bhh, float* __restrict__ ws)
{
    const int b = blockIdx.x, tid = threadIdx.x;
    if (b < 12) {
        // wi bf16 frags: b 0-3 = R a-tiles, 4-7 = Z, 8-11 = N; rows sigma-permuted
        if (tid < 64) {
            const int er = tid & 15, cp = tid >> 4;
            int g = b >> 2, a = b & 3;
            float s = (g == 2) ? 2.0f * LOG2E : LOG2E;
            const float* src = Wih + (size_t)(g * 64 + sigma_(a, er)) * 64 + 8 * cp;
            union { ushort u[8]; bf16x8 v; } fr;
            #pragma unroll
            for (int j = 0; j < 8; ++j) fr.u[j] = bf16rn(s * src[j]);
            *(bf16x8*)((char*)ws + WS_WI_B + ((size_t)b * 64 + tid) * 16) = fr.v;
        }
    } else if (b < 36) {
        // whh frags: rows sigma-permuted, k-columns unpermuted
        if (tid < 64) {
            const int er = tid & 15, cp = tid >> 4;
            int t = b - 12, g = t >> 3, r = t & 7, a = r >> 1, f = r & 1;
            float s = (g == 2) ? 2.0f * LOG2E : LOG2E;
            const float* src = Whh + (size_t)(g * 64 + sigma_(a, er)) * 64 + 32 * f + 8 * cp;
            union { ushort u[8]; bf16x8 v; } fr;
            #pragma unroll
            for (int j = 0; j < 8; ++j) fr.u[j] = bf16rn(s * src[j]);
            *(bf16x8*)((char*)ws + WS_WHH_B + ((size_t)t * 64 + tid) * 16) = fr.v;
        }
    } else if (b < 38) {
        // gic2[t][s]: slot s -> block (R/Z/Ni/bhn), permuted dim d
        const int base = (b - 36) * 3072;
        for (int i = tid; i < 3072; i += 256) {
            int idx = base + i, t = idx >> 8, s = idx & 255;
            int blk = s >> 6, s64 = s & 63;
            int d = sigma_(s64 >> 4, s64 & 15);
            float val;
            if (blk < 3) {
                int g = blk * 64 + d;
                float acc = bih[g] + (g < 128 ? bhh[g] : 0.0f);
                const float* ttr = tt + t * 32;
                const float* wr  = Wih + g * 64 + 32;
                #pragma unroll
                for (int k = 0; k < 32; ++k) {
                    float e = ttr[k];
                    e = fmaxf(e, 0.2f * e);
                    acc = fmaf(wr[k], e, acc);
                }
                val = acc * (g < 128 ? LOG2E : 2.0f * LOG2E);
            } else {
                val = 2.0f * LOG2E * bhh[128 + d];
            }
            ws[WS_GIC_F + idx] = val;
        }
    } else {
        if (tid < 96) ws[WS_WLC_F + tid] = (tid < 64) ? Wloc[tid] : bloc[tid - 64];
    }
}

// ------- main kernel: h register-resident; gic2 in LDS; no unroll -------
extern "C" __global__ void __launch_bounds__(512, 4)
traj_gru_mfma(const float* __restrict__ x, const float* __restrict__ ws,
              const float* __restrict__ Wpred, const float* __restrict__ bpred,
              float* __restrict__ out)
{
    extern __shared__ __align__(16) char L[];
    float* gicS = (float*)(L + L_GIC_OFF);
    char*  wiS  = L + L_WI_OFF;
    char*  whhS = L + L_WHH_OFF;
    float* wlcS = (float*)(L + L_WLC_OFF);

    const int tid  = threadIdx.x;
    const int lane = tid & 63;
    const int wid  = tid >> 6;       // wave 0..7
    const int er   = lane & 15;
    const int cp   = lane >> 4;

    // ---- stage tables ws -> LDS (coalesced) ----
    {
        const float4* g4 = (const float4*)(ws + WS_GIC_F);
        float4* s4 = (float4*)gicS;
        for (int i = tid; i < (TN * 256) / 4; i += 512) s4[i] = g4[i];
    }
    for (int i = tid; i < 36 * 64; i += 512) {
        int f = i >> 6, l = i & 63;
        if (f < 12)
            *(bf16x8*)(wiS + ((size_t)f * 64 + l) * 16) =
                *(const bf16x8*)((const char*)ws + WS_WI_B + (size_t)i * 16);
        else
            *(bf16x8*)(whhS + ((size_t)(f - 12) * 64 + l) * 16) =
                *(const bf16x8*)((const char*)ws + WS_WHH_B + ((size_t)(f - 12) * 64 + l) * 16);
    }
    if (tid < 96) wlcS[tid] = ws[WS_WLC_F + tid];
    __syncthreads();   // the only barrier

    const f32x2* wlc2 = (const f32x2*)wlcS;

    // ---- main loop: wave owns 16 elements; h state in registers ----
    const long long eg = (long long)(blockIdx.x * 8 + wid) * 16 + er;
    const float* xr = x + eg * (TN * 2);

    f32x2 hold2[4][2];           // f32 master state (permuted dims)
    uint  hf[8];                 // bf16 h pairs == next step's B-frag dwords
    #pragma unroll
    for (int a = 0; a < 4; ++a) {
        hf[2 * a] = 0u; hf[2 * a + 1] = 0u;
        #pragma unroll
        for (int p = 0; p < 2; ++p) hold2[a][p] = (f32x2){0.0f, 0.0f};
    }

    const f32x2 one2    = {1.0f, 1.0f};
    const f32x2 negtwo2 = {-2.0f, -2.0f};

    float2 xv = *(const float2*)(xr);   // t=0 prefetched

    #pragma unroll 1
    for (int t = 0; t < TN; ++t) {
        // accumulator init from gic2 (LDS), issued first; exf build hides latency
        const float* gt = gicS + t * 256;
        f32x4 accR[4], accZ[4], accNi[4], accNh[4];
        #pragma unroll
        for (int a = 0; a < 4; ++a) {
            accR[a]  = *(const f32x4*)(gt + a * 16 + 4 * cp);
            accZ[a]  = *(const f32x4*)(gt + 64 + a * 16 + 4 * cp);
            accNi[a] = *(const f32x4*)(gt + 128 + a * 16 + 4 * cp);
            accNh[a] = *(const f32x4*)(gt + 192 + a * 16 + 4 * cp);
        }

        const int tn = (t + 1 < TN) ? t + 1 : TN - 1;
        float2 xv_next = *(const float2*)(xr + tn * 2);

        // ex B-frag: ex[k = 8cp+j][elem = er]
        union { uint u[4]; bf16x8 v; } exf;
        {
            f32x2 xx = {xv.x, xv.x}, yy = {xv.y, xv.y};
            #pragma unroll
            for (int jp = 0; jp < 4; ++jp) {
                int kp = 4 * cp + jp;
                f32x2 w1 = wlc2[kp], w2 = wlc2[16 + kp], bl = wlc2[32 + kp];
                f32x2 v = __builtin_elementwise_fma(xx, w1,
                          __builtin_elementwise_fma(yy, w2, bl));
                exf.u[jp] = cvtpk_bf16(fmaxf(v.x, 0.2f * v.x), fmaxf(v.y, 0.2f * v.y));
            }
        }

        // input-part MFMAs (K=32), weights from LDS
        #pragma unroll
        for (int a = 0; a < 4; ++a) {
            bf16x8 wr = *(const bf16x8*)(wiS + ((size_t)a * 64 + lane) * 16);
            bf16x8 wz = *(const bf16x8*)(wiS + ((size_t)(4 + a) * 64 + lane) * 16);
            bf16x8 wn = *(const bf16x8*)(wiS + ((size_t)(8 + a) * 64 + lane) * 16);
            accR[a]  = __builtin_amdgcn_mfma_f32_16x16x32_bf16(wr, exf.v, accR[a], 0, 0, 0);
            accZ[a]  = __builtin_amdgcn_mfma_f32_16x16x32_bf16(wz, exf.v, accZ[a], 0, 0, 0);
            accNi[a] = __builtin_amdgcn_mfma_f32_16x16x32_bf16(wn, exf.v, accNi[a], 0, 0, 0);
        }

        // recurrent MFMAs: B-frags assembled directly from hf registers
        if (t > 0) {
            union { uint u[4]; bf16x8 v; } h0, h1;
            h0.u[0] = hf[0]; h0.u[1] = hf[1]; h0.u[2] = hf[2]; h0.u[3] = hf[3];
            h1.u[0] = hf[4]; h1.u[1] = hf[5]; h1.u[2] = hf[6]; h1.u[3] = hf[7];
            #pragma unroll
            for (int a = 0; a < 4; ++a) {
                bf16x8 wr0 = *(const bf16x8*)(whhS + ((size_t)(a * 2 + 0) * 64 + lane) * 16);
                bf16x8 wr1 = *(const bf16x8*)(whhS + ((size_t)(a * 2 + 1) * 64 + lane) * 16);
                accR[a] = __builtin_amdgcn_mfma_f32_16x16x32_bf16(wr0, h0.v, accR[a], 0, 0, 0);
                accR[a] = __builtin_amdgcn_mfma_f32_16x16x32_bf16(wr1, h1.v, accR[a], 0, 0, 0);
                bf16x8 wz0 = *(const bf16x8*)(whhS + ((size_t)(8 + a * 2 + 0) * 64 + lane) * 16);
                bf16x8 wz1 = *(const bf16x8*)(whhS + ((size_t)(8 + a * 2 + 1) * 64 + lane) * 16);
                accZ[a] = __builtin_amdgcn_mfma_f32_16x16x32_bf16(wz0, h0.v, accZ[a], 0, 0, 0);
                accZ[a] = __builtin_amdgcn_mfma_f32_16x16x32_bf16(wz1, h1.v, accZ[a], 0, 0, 0);
                bf16x8 wn0 = *(const bf16x8*)(whhS + ((size_t)(16 + a * 2 + 0) * 64 + lane) * 16);
                bf16x8 wn1 = *(const bf16x8*)(whhS + ((size_t)(16 + a * 2 + 1) * 64 + lane) * 16);
                accNh[a] = __builtin_amdgcn_mfma_f32_16x16x32_bf16(wn0, h0.v, accNh[a], 0, 0, 0);
                accNh[a] = __builtin_amdgcn_mfma_f32_16x16x32_bf16(wn1, h1.v, accNh[a], 0, 0, 0);
            }
        }

        // epilogue: packed-f32 gate math; h pairs -> hf registers (no LDS)
        #pragma unroll
        for (int a = 0; a < 4; ++a) {
            #pragma unroll
            for (int p = 0; p < 2; ++p) {
                f32x2 aR  = {accR[a][2 * p],  accR[a][2 * p + 1]};
                f32x2 aZ  = {accZ[a][2 * p],  accZ[a][2 * p + 1]};
                f32x2 aNi = {accNi[a][2 * p], accNi[a][2 * p + 1]};
                f32x2 aNh = {accNh[a][2 * p], accNh[a][2 * p + 1]};
                f32x2 eR = {exp2n_(aR.x), exp2n_(aR.y)};
                f32x2 eZ = {exp2n_(aZ.x), exp2n_(aZ.y)};
                f32x2 dR = eR + one2;
                f32x2 dZ = eZ + one2;
                f32x2 r  = {__builtin_amdgcn_rcpf(dR.x), __builtin_amdgcn_rcpf(dR.y)};
                f32x2 z  = {__builtin_amdgcn_rcpf(dZ.x), __builtin_amdgcn_rcpf(dZ.y)};
                f32x2 np = __builtin_elementwise_fma(r, aNh, aNi);     // 2log2e * npre
                f32x2 e2 = {exp2p_(np.x), exp2p_(np.y)};
                f32x2 d2 = e2 + one2;
                f32x2 rc = {__builtin_amdgcn_rcpf(d2.x), __builtin_amdgcn_rcpf(d2.y)};
                f32x2 n  = __builtin_elementwise_fma(rc, negtwo2, one2);  // tanh
                f32x2 hm = hold2[a][p] - n;
                f32x2 h  = __builtin_elementwise_fma(z, hm, n);
                hold2[a][p] = h;
                hf[2 * a + p] = cvtpk_bf16(h.x, h.y);
            }
        }

        xv = xv_next;
    }

    // ---- prediction head (Wpred read at permuted dims) ----
    float part = 0.0f;
    #pragma unroll
    for (int a = 0; a < 4; ++a) {
        #pragma unroll
        for (int p = 0; p < 2; ++p) {
            int base = 32 * (a >> 1) + 8 * cp + 4 * (a & 1) + 2 * p;
            f32x2 wp = *(const f32x2*)(Wpred + base);
            part = fmaf(hold2[a][p].x, wp.x, part);
            part = fmaf(hold2[a][p].y, wp.y, part);
        }
    }
    part += __shfl_xor(part, 16);
    part += __shfl_xor(part, 32);
    if (cp == 0) out[eg] = sigm(part + bpred[0]);
}

extern "C" void kernel_launch(void* const* d_in, const int* in_sizes, int n_in,
                              void* d_out, int out_size, void* d_ws, size_t ws_size,
                              hipStream_t stream) {
    const float* x     = (const float*)d_in[0];
    const float* Wloc  = (const float*)d_in[1];
    const float* bloc  = (const float*)d_in[2];
    const float* tt    = (const float*)d_in[3];
    const float* Wih   = (const float*)d_in[4];
    const float* Whh   = (const float*)d_in[5];
    const float* bih   = (const float*)d_in[6];
    const float* bhh   = (const float*)d_in[7];
    const float* Wpred = (const float*)d_in[8];
    const float* bpred = (const float*)d_in[9];
    float* out = (float*)d_out;
    float* ws  = (float*)d_ws;

    (void)hipFuncSetAttribute((const void*)traj_gru_mfma,
                              hipFuncAttributeMaxDynamicSharedMemorySize, LDS_BYTES);

    hipLaunchKernelGGL(traj_gru_pre, dim3(39), dim3(256), 0, stream,
                       Wloc, bloc, tt, Wih, Whh, bih, bhh, ws);
    // 65536 elements / (8 waves * 16 elem) = 512 blocks of 512 threads = 2 blocks/CU
    hipLaunchKernelGGL(traj_gru_mfma, dim3(512), dim3(512), LDS_BYTES, stream,
                       x, ws, Wpred, bpred, out);
}